// Round 1
// baseline (953.496 us; speedup 1.0000x reference)
//
#include <hip/hip_runtime.h>
#include <math.h>

namespace {

constexpr int HW    = 56 * 56;       // 3136
constexpr int NB    = 64;
constexpr int CTOT  = 256;
constexpr int CPG   = 16;            // channels per group
constexpr int GRP   = 16;
constexpr int MTOT  = NB * HW;       // 200704 positions per channel
constexpr int NPAIR = 136;           // upper triangle incl. diagonal of 16x16
constexpr int NACC  = CPG + NPAIR;   // 152 accumulators per group
constexpr float EPSR = 1e-4f;
constexpr int BPG1  = 32;            // blocks per group, stats pass (512 blocks = 2/CU)
constexpr int NS_IT = 14;            // Newton-Schulz iterations
constexpr int F4    = HW / 4;        // 784 float4 chunks per channel per image

__host__ __device__ constexpr int pair_idx(int i, int j) {
    return i * CPG - (i * (i - 1)) / 2 + (j - i);
}

// ---------------- Pass 1: raw channel sums + cross-product sums (one read of x) ------
// Scalar per-channel loads (16 live + 16 prefetch regs instead of 64 float4 regs):
// keeps the live set ~195 VGPRs -> no spill under the 256-reg cap; explicit
// next-iteration prefetch hides HBM latency under the 136-FMA chain.
__global__ __launch_bounds__(256, 2)
void cov_kernel(const float* __restrict__ x, float* __restrict__ accg) {
    const int g   = blockIdx.x / BPG1;
    const int b   = blockIdx.x % BPG1;
    const int tid = threadIdx.x;

    float sum[CPG];
    float acc[NPAIR];
#pragma unroll
    for (int i = 0; i < CPG; ++i) sum[i] = 0.f;
#pragma unroll
    for (int k = 0; k < NPAIR; ++k) acc[k] = 0.f;

    const int stride = BPG1 * 256;         // 8192 positions per step

    float v[CPG], vn[CPG];
    int m = b * 256 + tid;                 // < 8192 always, so first load is valid
    {
        const int n  = m / HW;
        const int hw = m - n * HW;
        const float* p = x + ((size_t)n * CTOT + (size_t)g * CPG) * HW + hw;
#pragma unroll
        for (int j = 0; j < CPG; ++j) v[j] = p[(size_t)j * HW];
    }

    while (true) {
        const int mn = m + stride;
        const bool more = (mn < MTOT);
        if (more) {
            const int n  = mn / HW;
            const int hw = mn - n * HW;
            const float* p = x + ((size_t)n * CTOT + (size_t)g * CPG) * HW + hw;
#pragma unroll
            for (int j = 0; j < CPG; ++j) vn[j] = p[(size_t)j * HW];
        }
#pragma unroll
        for (int i = 0; i < CPG; ++i) {
            sum[i] += v[i];
#pragma unroll
            for (int j = i; j < CPG; ++j)
                acc[pair_idx(i, j)] = fmaf(v[i], v[j], acc[pair_idx(i, j)]);
        }
        if (!more) break;
        m = mn;
#pragma unroll
        for (int j = 0; j < CPG; ++j) v[j] = vn[j];
    }

    // wave butterfly: every lane ends with the wave total
#pragma unroll
    for (int i = 0; i < CPG; ++i) {
#pragma unroll
        for (int s = 32; s > 0; s >>= 1) sum[i] += __shfl_xor(sum[i], s, 64);
    }
#pragma unroll
    for (int k = 0; k < NPAIR; ++k) {
#pragma unroll
        for (int s = 32; s > 0; s >>= 1) acc[k] += __shfl_xor(acc[k], s, 64);
    }

    __shared__ float red[4][NACC];
    const int wave = tid >> 6;
    const int lane = tid & 63;
    if (lane == 0) {
#pragma unroll
        for (int i = 0; i < CPG; ++i) red[wave][i] = sum[i];
#pragma unroll
        for (int k = 0; k < NPAIR; ++k) red[wave][CPG + k] = acc[k];
    }
    __syncthreads();
    if (tid < NACC) {
        const float v0 = red[0][tid] + red[1][tid] + red[2][tid] + red[3][tid];
        atomicAdd(&accg[g * NACC + tid], v0);
    }
}

// ---------------- Pass 2: Newton-Schulz inverse sqrt; fold weight/bias/mean in -------
// Outputs (TRANSPOSED for the apply pass): Pout[g][j][i] = w_i * (cov+eps I)^{-1/2}[i][j]
//          bf[g][i] = bias_i - sum_j P[i][j] * mu[j]
__global__ __launch_bounds__(256, 1)
void ns_kernel(const float* __restrict__ accg,
               const float* __restrict__ weight, const float* __restrict__ bias,
               float* __restrict__ Pout, float* __restrict__ bfout) {
    __shared__ float A[CPG][CPG], Y[CPG][CPG], Z[CPG][CPG], T[CPG][CPG];
    __shared__ float mu[CPG];
    __shared__ float s_tr;
    const int g = blockIdx.x;
    const int t = threadIdx.x;
    const int i = t >> 4, j = t & 15;
    const float* a = accg + g * NACC;
    const float invM = 1.0f / (float)MTOT;

    if (t < CPG) mu[t] = a[t] * invM;
    __syncthreads();
    {
        const int lo = i < j ? i : j;
        const int hi = i < j ? j : i;
        float c = a[CPG + pair_idx(lo, hi)] * invM - mu[i] * mu[j];
        if (i == j) c += EPSR;
        A[i][j] = c;
    }
    __syncthreads();
    if (t == 0) {
        float tr = 0.f;
        for (int k = 0; k < CPG; ++k) tr += A[k][k];
        s_tr = tr;
    }
    __syncthreads();
    const float tr = s_tr;
    Y[i][j] = A[i][j] / tr;
    Z[i][j] = (i == j) ? 1.f : 0.f;
    __syncthreads();

    for (int it = 0; it < NS_IT; ++it) {
        float zy = 0.f;
#pragma unroll
        for (int k = 0; k < CPG; ++k) zy += Z[i][k] * Y[k][j];
        const float tij = ((i == j) ? 1.5f : 0.f) - 0.5f * zy;
        T[i][j] = tij;
        __syncthreads();
        float y2 = 0.f, z2 = 0.f;
#pragma unroll
        for (int k = 0; k < CPG; ++k) {
            y2 += Y[i][k] * T[k][j];
            z2 += T[i][k] * Z[k][j];
        }
        __syncthreads();
        Y[i][j] = y2;
        Z[i][j] = z2;
        __syncthreads();
    }

    const float pw = (Z[i][j] / sqrtf(tr)) * weight[g * CPG + i];
    Pout[g * 256 + j * CPG + i] = pw;     // transposed: row j holds P[.][j]

    T[i][j] = pw;
    __syncthreads();
    if (t < CPG) {
        float o = 0.f;
        for (int k = 0; k < CPG; ++k) o += T[t][k] * mu[k];
        bfout[g * CPG + t] = bias[g * CPG + t] - o;
    }
}

// ---------------- Pass 3: out = Pw . x + bf  (register streaming, no x-LDS) ----------
// One block per (n,g) slab. Each thread owns float4 position-chunks and computes ALL
// 16 output channels from 16 privately-loaded input channels: x reuse lives in
// registers, P (1 KB) is a wave-uniform LDS broadcast read as float4 rows of P^T.
__global__ __launch_bounds__(256, 2)
void apply_kernel(const float* __restrict__ x, const float* __restrict__ Pg,
                  const float* __restrict__ bfg, float* __restrict__ out) {
    __shared__ float Pl[CPG * CPG];       // Pl[j*16+i] = P[i][j]
    __shared__ float bl[CPG];

    const int slab = blockIdx.x;
    const int g    = slab & (GRP - 1);
    const int n    = slab >> 4;
    const int t    = threadIdx.x;

    Pl[t] = Pg[g * 256 + t];
    if (t < CPG) bl[t] = bfg[g * CPG + t];
    __syncthreads();

    const size_t base = ((size_t)n * CTOT + (size_t)g * CPG) * HW;
    const float* xb = x + base;
    float*       ob = out + base;

    for (int f = t; f < F4; f += 256) {
        const float* px = xb + 4 * f;
        float4 xv[CPG];
#pragma unroll
        for (int j = 0; j < CPG; ++j)
            xv[j] = *(const float4*)(px + j * HW);   // 1 KiB/wave per j

        float4 acc[CPG];
#pragma unroll
        for (int i = 0; i < CPG; ++i) {
            const float bb = bl[i];
            acc[i] = make_float4(bb, bb, bb, bb);
        }

#pragma unroll
        for (int j = 0; j < CPG; ++j) {
            const float4* prow = (const float4*)&Pl[j * CPG];  // wave-uniform broadcast
            const float4 p0 = prow[0], p1 = prow[1], p2 = prow[2], p3 = prow[3];
            const float4 xj = xv[j];
#pragma unroll
            for (int q = 0; q < 4; ++q) {
                const float4 pq = (q == 0) ? p0 : (q == 1) ? p1 : (q == 2) ? p2 : p3;
                acc[q * 4 + 0].x = fmaf(pq.x, xj.x, acc[q * 4 + 0].x);
                acc[q * 4 + 0].y = fmaf(pq.x, xj.y, acc[q * 4 + 0].y);
                acc[q * 4 + 0].z = fmaf(pq.x, xj.z, acc[q * 4 + 0].z);
                acc[q * 4 + 0].w = fmaf(pq.x, xj.w, acc[q * 4 + 0].w);
                acc[q * 4 + 1].x = fmaf(pq.y, xj.x, acc[q * 4 + 1].x);
                acc[q * 4 + 1].y = fmaf(pq.y, xj.y, acc[q * 4 + 1].y);
                acc[q * 4 + 1].z = fmaf(pq.y, xj.z, acc[q * 4 + 1].z);
                acc[q * 4 + 1].w = fmaf(pq.y, xj.w, acc[q * 4 + 1].w);
                acc[q * 4 + 2].x = fmaf(pq.z, xj.x, acc[q * 4 + 2].x);
                acc[q * 4 + 2].y = fmaf(pq.z, xj.y, acc[q * 4 + 2].y);
                acc[q * 4 + 2].z = fmaf(pq.z, xj.z, acc[q * 4 + 2].z);
                acc[q * 4 + 2].w = fmaf(pq.z, xj.w, acc[q * 4 + 2].w);
                acc[q * 4 + 3].x = fmaf(pq.w, xj.x, acc[q * 4 + 3].x);
                acc[q * 4 + 3].y = fmaf(pq.w, xj.y, acc[q * 4 + 3].y);
                acc[q * 4 + 3].z = fmaf(pq.w, xj.z, acc[q * 4 + 3].z);
                acc[q * 4 + 3].w = fmaf(pq.w, xj.w, acc[q * 4 + 3].w);
            }
        }

#pragma unroll
        for (int i = 0; i < CPG; ++i)
            *(float4*)(ob + i * HW + 4 * f) = acc[i];
    }
}

} // namespace

extern "C" void kernel_launch(void* const* d_in, const int* in_sizes, int n_in,
                              void* d_out, int out_size, void* d_ws, size_t ws_size,
                              hipStream_t stream) {
    const float* x      = (const float*)d_in[0];
    const float* weight = (const float*)d_in[1];
    const float* bias   = (const float*)d_in[2];
    float* out = (float*)d_out;
    float* ws  = (float*)d_ws;

    float* acc = ws;            // 16 * 152 floats (padded region 2560)
    float* Pw  = ws + 2560;     // 16 * 256 floats
    float* bf  = ws + 6656;     // 16 * 16 floats

    hipMemsetAsync(acc, 0, GRP * NACC * sizeof(float), stream);

    cov_kernel<<<GRP * BPG1, 256, 0, stream>>>(x, acc);
    ns_kernel<<<GRP, 256, 0, stream>>>(acc, weight, bias, Pw, bf);
    apply_kernel<<<NB * GRP, 256, 0, stream>>>(x, Pw, bf, out);
}

// Round 2
// 655.629 us; speedup vs baseline: 1.4543x; 1.4543x over previous
//
#include <hip/hip_runtime.h>
#include <math.h>

namespace {

constexpr int HW    = 56 * 56;       // 3136
constexpr int NB    = 64;
constexpr int CTOT  = 256;
constexpr int CPG   = 16;            // channels per group
constexpr int GRP   = 16;
constexpr int MTOT  = NB * HW;       // 200704 positions per channel
constexpr int NPAIR = 136;           // upper triangle incl. diagonal of 16x16
constexpr int NACC  = CPG + NPAIR;   // 152 accumulators per group
constexpr float EPSR = 1e-4f;
constexpr int NS_IT = 14;            // Newton-Schulz iterations
constexpr int PPW   = NPAIR / 4;     // 34 pairs per wave
constexpr int F2    = HW / 2;        // 1568 float2 chunks per channel per image
constexpr int CITER = HW / 64;       // 49 position-steps per cov block

__host__ __device__ constexpr int pair_idx(int i, int j) {
    return i * CPG - (i * (i - 1)) / 2 + (j - i);
}

// ---------------- Pass 1: channel sums + cross-product sums (one read of x) ----------
// Pair-split across the 4 waves: each wave accumulates 34 of the 136 pairs plus 4 of
// the 16 channel sums. Live set ~85 VGPRs -> no spill (the v2 regression was spill
// traffic: VGPR capped at 128 with a ~200-reg live set). The 3 duplicate wave reads
// of the same 256 B runs are L1/L2 hits; HBM sees each x element once.
template<int W>
__device__ __forceinline__ void accum_pairs(const float (&v)[CPG],
                                            float (&acc)[PPW], float (&sum)[4]) {
#pragma unroll
    for (int i = 0; i < CPG; ++i) {
#pragma unroll
        for (int j = i; j < CPG; ++j) {
            const int k = pair_idx(i, j);            // unroll-constant
            if (k >= W * PPW && k < (W + 1) * PPW)   // folds at compile time
                acc[k - W * PPW] = fmaf(v[i], v[j], acc[k - W * PPW]);
        }
    }
#pragma unroll
    for (int c = 0; c < 4; ++c) sum[c] += v[W * 4 + c];
}

template<int W>
__device__ __forceinline__ void writeback(float* __restrict__ dst,
                                          const float (&acc)[PPW],
                                          const float (&sum)[4]) {
#pragma unroll
    for (int k = 0; k < PPW; ++k) atomicAdd(dst + CPG + W * PPW + k, acc[k]);
#pragma unroll
    for (int c = 0; c < 4; ++c) atomicAdd(dst + W * 4 + c, sum[c]);
}

__global__ __launch_bounds__(256)
void cov_kernel(const float* __restrict__ x, float* __restrict__ accg) {
    const int bid  = blockIdx.x;          // bid = g*NB + n
    const int g    = bid >> 6;
    const int n    = bid & (NB - 1);
    const int t    = threadIdx.x;
    const int w    = t >> 6;
    const int lane = t & 63;

    const float* xb = x + ((size_t)n * CTOT + (size_t)g * CPG) * HW;

    float acc[PPW], sum[4];
#pragma unroll
    for (int k = 0; k < PPW; ++k) acc[k] = 0.f;
#pragma unroll
    for (int c = 0; c < 4; ++c) sum[c] = 0.f;

    float v[CPG], vn[CPG];
#pragma unroll
    for (int j = 0; j < CPG; ++j) v[j] = xb[(size_t)j * HW + lane];

    for (int it = 0; it < CITER; ++it) {
        const bool more = (it + 1 < CITER);
        if (more) {
            const int hw = (it + 1) * 64 + lane;
#pragma unroll
            for (int j = 0; j < CPG; ++j) vn[j] = xb[(size_t)j * HW + hw];
        }
        if      (w == 0) accum_pairs<0>(v, acc, sum);
        else if (w == 1) accum_pairs<1>(v, acc, sum);
        else if (w == 2) accum_pairs<2>(v, acc, sum);
        else             accum_pairs<3>(v, acc, sum);
        if (!more) break;
#pragma unroll
        for (int j = 0; j < CPG; ++j) v[j] = vn[j];
    }

    // wave butterfly: every lane ends with the wave total
#pragma unroll
    for (int k = 0; k < PPW; ++k) {
#pragma unroll
        for (int s = 32; s > 0; s >>= 1) acc[k] += __shfl_xor(acc[k], s, 64);
    }
#pragma unroll
    for (int c = 0; c < 4; ++c) {
#pragma unroll
        for (int s = 32; s > 0; s >>= 1) sum[c] += __shfl_xor(sum[c], s, 64);
    }

    if (lane == 0) {
        float* dst = accg + g * NACC;
        if      (w == 0) writeback<0>(dst, acc, sum);
        else if (w == 1) writeback<1>(dst, acc, sum);
        else if (w == 2) writeback<2>(dst, acc, sum);
        else             writeback<3>(dst, acc, sum);
    }
}

// ---------------- Pass 2: Newton-Schulz inverse sqrt; fold weight/bias/mean in -------
// Outputs (TRANSPOSED for the apply pass): Pout[g][j][i] = w_i * (cov+eps I)^{-1/2}[i][j]
//          bf[g][i] = bias_i - sum_j P[i][j] * mu[j]
__global__ __launch_bounds__(256, 1)
void ns_kernel(const float* __restrict__ accg,
               const float* __restrict__ weight, const float* __restrict__ bias,
               float* __restrict__ Pout, float* __restrict__ bfout) {
    __shared__ float A[CPG][CPG], Y[CPG][CPG], Z[CPG][CPG], T[CPG][CPG];
    __shared__ float mu[CPG];
    __shared__ float s_tr;
    const int g = blockIdx.x;
    const int t = threadIdx.x;
    const int i = t >> 4, j = t & 15;
    const float* a = accg + g * NACC;
    const float invM = 1.0f / (float)MTOT;

    if (t < CPG) mu[t] = a[t] * invM;
    __syncthreads();
    {
        const int lo = i < j ? i : j;
        const int hi = i < j ? j : i;
        float c = a[CPG + pair_idx(lo, hi)] * invM - mu[i] * mu[j];
        if (i == j) c += EPSR;
        A[i][j] = c;
    }
    __syncthreads();
    if (t == 0) {
        float tr = 0.f;
        for (int k = 0; k < CPG; ++k) tr += A[k][k];
        s_tr = tr;
    }
    __syncthreads();
    const float tr = s_tr;
    Y[i][j] = A[i][j] / tr;
    Z[i][j] = (i == j) ? 1.f : 0.f;
    __syncthreads();

    for (int it = 0; it < NS_IT; ++it) {
        float zy = 0.f;
#pragma unroll
        for (int k = 0; k < CPG; ++k) zy += Z[i][k] * Y[k][j];
        const float tij = ((i == j) ? 1.5f : 0.f) - 0.5f * zy;
        T[i][j] = tij;
        __syncthreads();
        float y2 = 0.f, z2 = 0.f;
#pragma unroll
        for (int k = 0; k < CPG; ++k) {
            y2 += Y[i][k] * T[k][j];
            z2 += T[i][k] * Z[k][j];
        }
        __syncthreads();
        Y[i][j] = y2;
        Z[i][j] = z2;
        __syncthreads();
    }

    const float pw = (Z[i][j] / sqrtf(tr)) * weight[g * CPG + i];
    Pout[g * 256 + j * CPG + i] = pw;     // transposed: row j holds column P[.][j]

    T[i][j] = pw;
    __syncthreads();
    if (t < CPG) {
        float o = 0.f;
        for (int k = 0; k < CPG; ++k) o += T[t][k] * mu[k];
        bfout[g * CPG + t] = bias[g * CPG + t] - o;
    }
}

// ---------------- Pass 3: out = Pw . x + bf  (float2 register streaming) -------------
// One block per (n,g) slab. Each lane owns float2 position chunks and computes ALL 16
// output channels: acc[16] float2 (32 regs) + xv[16] float2 (32 regs) ~= 85 live regs,
// no spill. Loads/stores are 512 B per wave instruction, each x element touched once.
__global__ __launch_bounds__(256)
void apply_kernel(const float* __restrict__ x, const float* __restrict__ Pg,
                  const float* __restrict__ bfg, float* __restrict__ out) {
    __shared__ __align__(16) float Pl[CPG * CPG];   // Pl[j*16+i] = P[i][j]
    __shared__ float bl[CPG];

    const int slab = blockIdx.x;
    const int g    = slab & (GRP - 1);
    const int n    = slab >> 4;
    const int t    = threadIdx.x;

    Pl[t] = Pg[g * 256 + t];
    if (t < CPG) bl[t] = bfg[g * CPG + t];
    __syncthreads();

    const size_t base = ((size_t)n * CTOT + (size_t)g * CPG) * HW;
    const float* xb = x + base;
    float*       ob = out + base;

    for (int f2 = t; f2 < F2; f2 += 256) {
        const float* px = xb + 2 * f2;
        float2 xv[CPG];
#pragma unroll
        for (int j = 0; j < CPG; ++j)
            xv[j] = *(const float2*)(px + j * HW);

        float2 acc[CPG];
#pragma unroll
        for (int i = 0; i < CPG; ++i) {
            const float bb = bl[i];
            acc[i] = make_float2(bb, bb);
        }

#pragma unroll
        for (int j = 0; j < CPG; ++j) {
            const float2 xj = xv[j];
            const float4* pc = (const float4*)&Pl[j * CPG];  // column j, wave-uniform
#pragma unroll
            for (int q = 0; q < 4; ++q) {
                const float4 p = pc[q];
                acc[q * 4 + 0].x = fmaf(p.x, xj.x, acc[q * 4 + 0].x);
                acc[q * 4 + 0].y = fmaf(p.x, xj.y, acc[q * 4 + 0].y);
                acc[q * 4 + 1].x = fmaf(p.y, xj.x, acc[q * 4 + 1].x);
                acc[q * 4 + 1].y = fmaf(p.y, xj.y, acc[q * 4 + 1].y);
                acc[q * 4 + 2].x = fmaf(p.z, xj.x, acc[q * 4 + 2].x);
                acc[q * 4 + 2].y = fmaf(p.z, xj.y, acc[q * 4 + 2].y);
                acc[q * 4 + 3].x = fmaf(p.w, xj.x, acc[q * 4 + 3].x);
                acc[q * 4 + 3].y = fmaf(p.w, xj.y, acc[q * 4 + 3].y);
            }
        }

        float* po = ob + 2 * f2;
#pragma unroll
        for (int i = 0; i < CPG; ++i)
            *(float2*)(po + i * HW) = acc[i];
    }
}

} // namespace

extern "C" void kernel_launch(void* const* d_in, const int* in_sizes, int n_in,
                              void* d_out, int out_size, void* d_ws, size_t ws_size,
                              hipStream_t stream) {
    const float* x      = (const float*)d_in[0];
    const float* weight = (const float*)d_in[1];
    const float* bias   = (const float*)d_in[2];
    float* out = (float*)d_out;
    float* ws  = (float*)d_ws;

    float* acc = ws;            // 16 * 152 floats (padded region 2560)
    float* Pw  = ws + 2560;     // 16 * 256 floats
    float* bf  = ws + 6656;     // 16 * 16 floats

    hipMemsetAsync(acc, 0, GRP * NACC * sizeof(float), stream);

    cov_kernel<<<GRP * NB, 256, 0, stream>>>(x, acc);
    ns_kernel<<<GRP, 256, 0, stream>>>(acc, weight, bias, Pw, bf);
    apply_kernel<<<NB * GRP, 256, 0, stream>>>(x, Pw, bf, out);
}

// Round 3
// 642.718 us; speedup vs baseline: 1.4835x; 1.0201x over previous
//
#include <hip/hip_runtime.h>
#include <math.h>

namespace {

constexpr int HW    = 56 * 56;       // 3136
constexpr int NB    = 64;
constexpr int CTOT  = 256;
constexpr int CPG   = 16;            // channels per group
constexpr int GRP   = 16;
constexpr int MTOT  = NB * HW;       // 200704 positions per channel
constexpr int NPAIR = 136;           // upper triangle incl. diagonal of 16x16
constexpr int NACC  = CPG + NPAIR;   // 152 accumulators per group
constexpr float EPSR = 1e-4f;
constexpr int NS_IT = 14;            // Newton-Schulz iterations
constexpr int PPW   = NPAIR / 4;     // 34 pairs per wave
constexpr int F2    = HW / 2;        // 1568 float2 chunks per channel per image
constexpr int CTILE = 256;           // cov stage tile: positions per tile
constexpr int NTILE = (HW + CTILE - 1) / CTILE;   // 13 (12 full + 1x64)

__host__ __device__ constexpr int pair_idx(int i, int j) {
    return i * CPG - (i * (i - 1)) / 2 + (j - i);
}

#define GLL16(src, dst)                                                        \
    __builtin_amdgcn_global_load_lds(                                          \
        (const __attribute__((address_space(1))) void*)(src),                  \
        (__attribute__((address_space(3))) void*)(dst), 16, 0, 0)

// ---------------- Pass 1: channel sums + cross-product sums (one read of x) ----------
// LDS-staged: each block owns one (g,n) slab; tiles of 16ch x 256pos staged via
// global_load_lds (1 KiB/inst), double-buffered. The 4 pair-split waves then read the
// SAME tile from LDS (69 TB/s pipe) instead of re-fetching drifted HBM runs -- round-2's
// cov had no lockstep, so the 4x wave duplication hit HBM, not L1. Registers:
// acc[34]+sum[4]+transient v2[16] ~= 85 live -> high occupancy, no spill.
template<int W>
__device__ __forceinline__ void accum2(const float2 (&v)[CPG],
                                       float (&acc)[PPW], float (&sum)[4]) {
#pragma unroll
    for (int i = 0; i < CPG; ++i) {
#pragma unroll
        for (int j = i; j < CPG; ++j) {
            const int k = pair_idx(i, j);            // unroll-constant
            if (k >= W * PPW && k < (W + 1) * PPW) { // folds at compile time
                acc[k - W * PPW] = fmaf(v[i].x, v[j].x, acc[k - W * PPW]);
                acc[k - W * PPW] = fmaf(v[i].y, v[j].y, acc[k - W * PPW]);
            }
        }
    }
#pragma unroll
    for (int c = 0; c < 4; ++c) sum[c] += v[W * 4 + c].x + v[W * 4 + c].y;
}

template<int W>
__device__ __forceinline__ void writeback(float* __restrict__ dst,
                                          const float (&acc)[PPW],
                                          const float (&sum)[4]) {
#pragma unroll
    for (int k = 0; k < PPW; ++k) atomicAdd(dst + CPG + W * PPW + k, acc[k]);
#pragma unroll
    for (int c = 0; c < 4; ++c) atomicAdd(dst + W * 4 + c, sum[c]);
}

__global__ __launch_bounds__(256)
void cov_kernel(const float* __restrict__ x, float* __restrict__ accg) {
    __shared__ __align__(16) float xs[2][CPG][CTILE];   // 32 KB, double-buffered

    const int bid  = blockIdx.x;          // bid = g*NB + n
    const int g    = bid >> 6;
    const int n    = bid & (NB - 1);
    const int t    = threadIdx.x;
    const int w    = t >> 6;
    const int lane = t & 63;

    const float* xb = x + ((size_t)n * CTOT + (size_t)g * CPG) * HW;

    float acc[PPW], sum[4];
#pragma unroll
    for (int k = 0; k < PPW; ++k) acc[k] = 0.f;
#pragma unroll
    for (int c = 0; c < 4; ++c) sum[c] = 0.f;

    // wave w stages channels 4w..4w+3: lane writes bytes [16*lane,16*lane+16) of row j
    auto stage = [&](int buf, int tile) {
        const int pos0 = tile * CTILE;
        const int len  = HW - pos0 < CTILE ? HW - pos0 : CTILE;   // 256 or 64
#pragma unroll
        for (int jj = 0; jj < 4; ++jj) {
            const int j = w * 4 + jj;
            if (4 * lane < len)
                GLL16(xb + (size_t)j * HW + pos0 + 4 * lane, &xs[buf][j][0]);
        }
    };

    stage(0, 0);
    __syncthreads();                      // drains vmcnt; tile 0 visible

    int cur = 0;
    for (int tile = 0; tile < NTILE; ++tile) {
        if (tile + 1 < NTILE) stage(cur ^ 1, tile + 1);   // issue-early DMA
        const int pos0 = tile * CTILE;
        const int len  = HW - pos0 < CTILE ? HW - pos0 : CTILE;
#pragma unroll
        for (int h = 0; h < 2; ++h) {
            const int p = h * 128 + 2 * lane;
            if (p < len) {
                float2 v2[CPG];
#pragma unroll
                for (int j = 0; j < CPG; ++j)
                    v2[j] = *(const float2*)&xs[cur][j][p];
                if      (w == 0) accum2<0>(v2, acc, sum);
                else if (w == 1) accum2<1>(v2, acc, sum);
                else if (w == 2) accum2<2>(v2, acc, sum);
                else             accum2<3>(v2, acc, sum);
            }
        }
        __syncthreads();                  // drains vmcnt (next tile landed) + publishes
        cur ^= 1;
    }

    // wave butterfly: every lane ends with the wave total
#pragma unroll
    for (int k = 0; k < PPW; ++k) {
#pragma unroll
        for (int s = 32; s > 0; s >>= 1) acc[k] += __shfl_xor(acc[k], s, 64);
    }
#pragma unroll
    for (int c = 0; c < 4; ++c) {
#pragma unroll
        for (int s = 32; s > 0; s >>= 1) sum[c] += __shfl_xor(sum[c], s, 64);
    }

    if (lane == 0) {
        float* dst = accg + g * NACC;
        if      (w == 0) writeback<0>(dst, acc, sum);
        else if (w == 1) writeback<1>(dst, acc, sum);
        else if (w == 2) writeback<2>(dst, acc, sum);
        else             writeback<3>(dst, acc, sum);
    }
}

// ---------------- Pass 2: Newton-Schulz inverse sqrt; fold weight/bias/mean in -------
// Outputs (TRANSPOSED for the apply pass): Pout[g][j][i] = w_i * (cov+eps I)^{-1/2}[i][j]
//          bf[g][i] = bias_i - sum_j P[i][j] * mu[j]
__global__ __launch_bounds__(256, 1)
void ns_kernel(const float* __restrict__ accg,
               const float* __restrict__ weight, const float* __restrict__ bias,
               float* __restrict__ Pout, float* __restrict__ bfout) {
    __shared__ float A[CPG][CPG], Y[CPG][CPG], Z[CPG][CPG], T[CPG][CPG];
    __shared__ float mu[CPG];
    __shared__ float s_tr;
    const int g = blockIdx.x;
    const int t = threadIdx.x;
    const int i = t >> 4, j = t & 15;
    const float* a = accg + g * NACC;
    const float invM = 1.0f / (float)MTOT;

    if (t < CPG) mu[t] = a[t] * invM;
    __syncthreads();
    {
        const int lo = i < j ? i : j;
        const int hi = i < j ? j : i;
        float c = a[CPG + pair_idx(lo, hi)] * invM - mu[i] * mu[j];
        if (i == j) c += EPSR;
        A[i][j] = c;
    }
    __syncthreads();
    if (t == 0) {
        float tr = 0.f;
        for (int k = 0; k < CPG; ++k) tr += A[k][k];
        s_tr = tr;
    }
    __syncthreads();
    const float tr = s_tr;
    Y[i][j] = A[i][j] / tr;
    Z[i][j] = (i == j) ? 1.f : 0.f;
    __syncthreads();

    for (int it = 0; it < NS_IT; ++it) {
        float zy = 0.f;
#pragma unroll
        for (int k = 0; k < CPG; ++k) zy += Z[i][k] * Y[k][j];
        const float tij = ((i == j) ? 1.5f : 0.f) - 0.5f * zy;
        T[i][j] = tij;
        __syncthreads();
        float y2 = 0.f, z2 = 0.f;
#pragma unroll
        for (int k = 0; k < CPG; ++k) {
            y2 += Y[i][k] * T[k][j];
            z2 += T[i][k] * Z[k][j];
        }
        __syncthreads();
        Y[i][j] = y2;
        Z[i][j] = z2;
        __syncthreads();
    }

    const float pw = (Z[i][j] / sqrtf(tr)) * weight[g * CPG + i];
    Pout[g * 256 + j * CPG + i] = pw;     // transposed: row j holds column P[.][j]

    T[i][j] = pw;
    __syncthreads();
    if (t < CPG) {
        float o = 0.f;
        for (int k = 0; k < CPG; ++k) o += T[t][k] * mu[k];
        bfout[g * CPG + t] = bias[g * CPG + t] - o;
    }
}

// ---------------- Pass 3: out = Pw . x + bf  (float2 register streaming) -------------
// One block per (n,g) slab; each lane owns float2 position chunks and computes ALL 16
// output channels. `#pragma unroll 1` is the round-2 fix: the ~6-trip grid-stride loop
// was fully unrolled by the compiler -> VGPR 256, 2 blocks/CU, spill traffic. Keeping
// one iteration live (~100 regs) gets 4 blocks/CU = 16 waves/CU, enough TLP to cover
// HBM latency (16 independent 512 B wave-loads in flight per wave).
__global__ __launch_bounds__(256)
void apply_kernel(const float* __restrict__ x, const float* __restrict__ Pg,
                  const float* __restrict__ bfg, float* __restrict__ out) {
    __shared__ __align__(16) float Pl[CPG * CPG];   // Pl[j*16+i] = P[i][j]
    __shared__ float bl[CPG];

    const int slab = blockIdx.x;
    const int g    = slab & (GRP - 1);
    const int n    = slab >> 4;
    const int t    = threadIdx.x;

    Pl[t] = Pg[g * 256 + t];
    if (t < CPG) bl[t] = bfg[g * CPG + t];
    __syncthreads();

    const size_t base = ((size_t)n * CTOT + (size_t)g * CPG) * HW;
    const float* xb = x + base;
    float*       ob = out + base;

#pragma unroll 1
    for (int f2 = t; f2 < F2; f2 += 256) {
        const float* px = xb + 2 * f2;
        float2 xv[CPG];
#pragma unroll
        for (int j = 0; j < CPG; ++j)
            xv[j] = *(const float2*)(px + j * HW);

        float2 acc[CPG];
#pragma unroll
        for (int i = 0; i < CPG; ++i) {
            const float bb = bl[i];
            acc[i] = make_float2(bb, bb);
        }

#pragma unroll
        for (int j = 0; j < CPG; ++j) {
            const float2 xj = xv[j];
            const float4* pc = (const float4*)&Pl[j * CPG];  // column j, wave-uniform
#pragma unroll
            for (int q = 0; q < 4; ++q) {
                const float4 p = pc[q];
                acc[q * 4 + 0].x = fmaf(p.x, xj.x, acc[q * 4 + 0].x);
                acc[q * 4 + 0].y = fmaf(p.x, xj.y, acc[q * 4 + 0].y);
                acc[q * 4 + 1].x = fmaf(p.y, xj.x, acc[q * 4 + 1].x);
                acc[q * 4 + 1].y = fmaf(p.y, xj.y, acc[q * 4 + 1].y);
                acc[q * 4 + 2].x = fmaf(p.z, xj.x, acc[q * 4 + 2].x);
                acc[q * 4 + 2].y = fmaf(p.z, xj.y, acc[q * 4 + 2].y);
                acc[q * 4 + 3].x = fmaf(p.w, xj.x, acc[q * 4 + 3].x);
                acc[q * 4 + 3].y = fmaf(p.w, xj.y, acc[q * 4 + 3].y);
            }
        }

        float* po = ob + 2 * f2;
#pragma unroll
        for (int i = 0; i < CPG; ++i)
            *(float2*)(po + i * HW) = acc[i];
    }
}

} // namespace

extern "C" void kernel_launch(void* const* d_in, const int* in_sizes, int n_in,
                              void* d_out, int out_size, void* d_ws, size_t ws_size,
                              hipStream_t stream) {
    const float* x      = (const float*)d_in[0];
    const float* weight = (const float*)d_in[1];
    const float* bias   = (const float*)d_in[2];
    float* out = (float*)d_out;
    float* ws  = (float*)d_ws;

    float* acc = ws;            // 16 * 152 floats (padded region 2560)
    float* Pw  = ws + 2560;     // 16 * 256 floats
    float* bf  = ws + 6656;     // 16 * 16 floats

    hipMemsetAsync(acc, 0, GRP * NACC * sizeof(float), stream);

    cov_kernel<<<GRP * NB, 256, 0, stream>>>(x, acc);
    ns_kernel<<<GRP, 256, 0, stream>>>(acc, weight, bias, Pw, bf);
    apply_kernel<<<NB * GRP, 256, 0, stream>>>(x, Pw, bf, out);
}